// Round 1
// baseline (338.987 us; speedup 1.0000x reference)
//
#include <hip/hip_runtime.h>

// Actor MLP, B=262144 rows:
//   per row: 14 groups x (9 ->16 relu -> 4 relu, shared W1/W2)
//   concat(56 shared outputs + 1 sale) -> 57x128 relu -> 128x30
//   out[:15] -> tanh (action_mean), out[15:] -> exp (action_std)
// One thread per row. z[128] accumulated directly (combined[57] never
// materialized). All weight reads are wave-uniform -> scalar (SGPR) loads.

constexpr int NG = 14;   // NUM_GROUPS
constexpr int GI = 9;    // GROUP_IN
constexpr int SH = 16;   // SHARED_H
constexpr int SO = 4;    // SHARED_OUT
constexpr int FH = 128;  // FINAL_H
constexpr int AD = 15;   // ACTION_DIM

__global__ __launch_bounds__(256) void actor_fused(
    const float* __restrict__ x,     // [B, 126]
    const float* __restrict__ sale,  // [B, 1]
    const float* __restrict__ W1,    // [9, 16]
    const float* __restrict__ b1,    // [16]
    const float* __restrict__ W2,    // [16, 4]
    const float* __restrict__ b2,    // [4]
    const float* __restrict__ W3,    // [57, 128]
    const float* __restrict__ b3,    // [128]
    const float* __restrict__ W4,    // [128, 30]
    const float* __restrict__ b4,    // [30]
    float* __restrict__ om,          // [B, 15] action_mean
    float* __restrict__ os,          // [B, 15] action_std
    int B)
{
    int b = blockIdx.x * 256 + threadIdx.x;
    if (b >= B) return;
    const float* xr = x + (size_t)b * (NG * GI);

    // z = b3 (final hidden pre-activation accumulator)
    float z[FH];
    #pragma unroll
    for (int j = 0; j < FH; ++j) z[j] = b3[j];

    // Phase 1+2a fused: shared block per group, immediately scatter s into z.
    #pragma unroll 1
    for (int g = 0; g < NG; ++g) {
        float in[GI];
        #pragma unroll
        for (int i = 0; i < GI; ++i) in[i] = xr[g * GI + i];

        float h[SH];
        #pragma unroll
        for (int j = 0; j < SH; ++j) {
            float a = b1[j];
            #pragma unroll
            for (int i = 0; i < GI; ++i) a = fmaf(in[i], W1[i * SH + j], a);
            h[j] = fmaxf(a, 0.f);
        }

        #pragma unroll
        for (int o = 0; o < SO; ++o) {
            float a = b2[o];
            #pragma unroll
            for (int i = 0; i < SH; ++i) a = fmaf(h[i], W2[i * SO + o], a);
            float s = fmaxf(a, 0.f);
            const float* w3r = W3 + (g * SO + o) * FH;  // uniform -> s_load
            #pragma unroll
            for (int j = 0; j < FH; ++j) z[j] = fmaf(s, w3r[j], z[j]);
        }
    }

    // sale contribution (combined index 56)
    {
        float s = sale[b];
        const float* w3r = W3 + 56 * FH;
        #pragma unroll
        for (int j = 0; j < FH; ++j) z[j] = fmaf(s, w3r[j], z[j]);
    }

    // relu z
    #pragma unroll
    for (int j = 0; j < FH; ++j) z[j] = fmaxf(z[j], 0.f);

    // out[k] = z . W4[:,k] + b4[k]; k runtime (uniform), j static (z in regs)
    #pragma unroll 1
    for (int k = 0; k < 2 * AD; ++k) {
        float a0 = 0.f, a1 = 0.f, a2 = 0.f, a3 = 0.f;
        #pragma unroll
        for (int j = 0; j < FH; j += 4) {
            a0 = fmaf(z[j + 0], W4[(j + 0) * 30 + k], a0);
            a1 = fmaf(z[j + 1], W4[(j + 1) * 30 + k], a1);
            a2 = fmaf(z[j + 2], W4[(j + 2) * 30 + k], a2);
            a3 = fmaf(z[j + 3], W4[(j + 3) * 30 + k], a3);
        }
        float v = ((a0 + a1) + (a2 + a3)) + b4[k];
        if (k < AD) {
            // tanh(v) = (e^{2v}-1)/(e^{2v}+1), clamped to avoid inf/inf
            float t = fminf(fmaxf(v, -20.f), 20.f);
            float e = __expf(2.f * t);
            om[(size_t)b * AD + k] = (e - 1.f) / (e + 1.f);
        } else {
            os[(size_t)b * AD + (k - AD)] = __expf(v);
        }
    }
}

extern "C" void kernel_launch(void* const* d_in, const int* in_sizes, int n_in,
                              void* d_out, int out_size, void* d_ws, size_t ws_size,
                              hipStream_t stream) {
    const float* x    = (const float*)d_in[0];
    const float* sale = (const float*)d_in[1];
    const float* W1   = (const float*)d_in[2];
    const float* b1   = (const float*)d_in[3];
    const float* W2   = (const float*)d_in[4];
    const float* b2   = (const float*)d_in[5];
    const float* W3   = (const float*)d_in[6];
    const float* b3   = (const float*)d_in[7];
    const float* W4   = (const float*)d_in[8];
    const float* b4   = (const float*)d_in[9];

    int B = in_sizes[1];  // sale_predictions is [B,1] -> B elements
    float* om = (float*)d_out;                 // action_mean flat [B*15]
    float* os = om + (size_t)B * AD;           // action_std  flat [B*15]

    int grid = (B + 255) / 256;
    actor_fused<<<grid, 256, 0, stream>>>(x, sale, W1, b1, W2, b2, W3, b3,
                                          W4, b4, om, os, B);
}

// Round 2
// 315.082 us; speedup vs baseline: 1.0759x; 1.0759x over previous
//
#include <hip/hip_runtime.h>

// Actor MLP, B=262144 rows, fp32:
//   per row: 14 groups x (9->16 relu ->4 relu, shared W1/W2)
//   concat(56+1 sale) -> 57x128 relu -> 128x30 -> tanh/exp split.
// One thread per row. z[128] held as 8 named ext_vector(16) SSA values so it
// can NEVER be demoted to scratch (R1 failure: z[128] array -> alloca -> 427us
// scratch-bound, VGPR=88). All weight reads wave-uniform -> s_load. W4 is
// transposed into d_ws once per launch so the final layer reads contiguous rows.

typedef float f16v __attribute__((ext_vector_type(16)));
typedef float f4v  __attribute__((ext_vector_type(4)));

constexpr int NG = 14, GI = 9, SH = 16, SO = 4, FH = 128, AD = 15;

__global__ void w4t_kernel(const float* __restrict__ W4, float* __restrict__ W4T) {
    int t = blockIdx.x * 256 + threadIdx.x;
    if (t < FH * 2 * AD) {
        int j = t / (2 * AD), k = t % (2 * AD);   // W4[j][k]
        W4T[(size_t)k * FH + j] = W4[t];
    }
}

__global__ __launch_bounds__(256) void actor_fused(
    const float* __restrict__ x,     // [B,126]
    const float* __restrict__ sale,  // [B,1]
    const float* __restrict__ W1,    // [9,16]
    const float* __restrict__ b1,    // [16]
    const float* __restrict__ W2,    // [16,4]
    const float* __restrict__ b2,    // [4]
    const float* __restrict__ W3,    // [57,128]
    const float* __restrict__ b3,    // [128]
    const float* __restrict__ W4T,   // [30,128] (transposed, in ws)
    const float* __restrict__ b4,    // [30]
    float* __restrict__ om, float* __restrict__ os, int B)
{
    int b = blockIdx.x * blockDim.x + threadIdx.x;
    if (b >= B) return;
    const float* xr = x + (size_t)b * (NG * GI);

    const f16v* b3v = (const f16v*)b3;
    f16v z0 = b3v[0], z1 = b3v[1], z2 = b3v[2], z3 = b3v[3],
         z4 = b3v[4], z5 = b3v[5], z6 = b3v[6], z7 = b3v[7];

    const f16v* w1v = (const f16v*)W1;   // row i = 16 floats
    const f4v*  w2v = (const f4v*)W2;    // row i = 4 floats
    const f16v  b1v = *(const f16v*)b1;
    const f4v   b2v = *(const f4v*)b2;

    // software-pipelined input row (9 named scalars, one group ahead)
    float c0 = xr[0], c1 = xr[1], c2 = xr[2], c3 = xr[3], c4 = xr[4],
          c5 = xr[5], c6 = xr[6], c7 = xr[7], c8 = xr[8];

    #pragma unroll 1
    for (int g = 0; g < NG; ++g) {
        float n0, n1, n2, n3, n4, n5, n6, n7, n8;
        if (g + 1 < NG) {
            const float* xn = xr + (g + 1) * GI;
            n0 = xn[0]; n1 = xn[1]; n2 = xn[2]; n3 = xn[3]; n4 = xn[4];
            n5 = xn[5]; n6 = xn[6]; n7 = xn[7]; n8 = xn[8];
        } else {
            n0 = n1 = n2 = n3 = n4 = n5 = n6 = n7 = n8 = 0.f;
        }

        // h = relu(b1 + x_g @ W1)
        f16v h = b1v;
        h += c0 * w1v[0]; h += c1 * w1v[1]; h += c2 * w1v[2];
        h += c3 * w1v[3]; h += c4 * w1v[4]; h += c5 * w1v[5];
        h += c6 * w1v[6]; h += c7 * w1v[7]; h += c8 * w1v[8];
        h = __builtin_elementwise_max(h, (f16v)0.f);

        // s = relu(b2 + h @ W2)
        f4v s = b2v;
        s += h[0]  * w2v[0];  s += h[1]  * w2v[1];  s += h[2]  * w2v[2];  s += h[3]  * w2v[3];
        s += h[4]  * w2v[4];  s += h[5]  * w2v[5];  s += h[6]  * w2v[6];  s += h[7]  * w2v[7];
        s += h[8]  * w2v[8];  s += h[9]  * w2v[9];  s += h[10] * w2v[10]; s += h[11] * w2v[11];
        s += h[12] * w2v[12]; s += h[13] * w2v[13]; s += h[14] * w2v[14]; s += h[15] * w2v[15];
        s = __builtin_elementwise_max(s, (f4v)0.f);

        // z += s_o * W3row(g*4+o), o=0..3
        const f16v* w3v = (const f16v*)(W3 + (size_t)(g * SO) * FH);
        float t0 = s[0], t1 = s[1], t2 = s[2], t3 = s[3];
        z0 += t0 * w3v[0];  z1 += t0 * w3v[1];  z2 += t0 * w3v[2];  z3 += t0 * w3v[3];
        z4 += t0 * w3v[4];  z5 += t0 * w3v[5];  z6 += t0 * w3v[6];  z7 += t0 * w3v[7];
        z0 += t1 * w3v[8];  z1 += t1 * w3v[9];  z2 += t1 * w3v[10]; z3 += t1 * w3v[11];
        z4 += t1 * w3v[12]; z5 += t1 * w3v[13]; z6 += t1 * w3v[14]; z7 += t1 * w3v[15];
        z0 += t2 * w3v[16]; z1 += t2 * w3v[17]; z2 += t2 * w3v[18]; z3 += t2 * w3v[19];
        z4 += t2 * w3v[20]; z5 += t2 * w3v[21]; z6 += t2 * w3v[22]; z7 += t2 * w3v[23];
        z0 += t3 * w3v[24]; z1 += t3 * w3v[25]; z2 += t3 * w3v[26]; z3 += t3 * w3v[27];
        z4 += t3 * w3v[28]; z5 += t3 * w3v[29]; z6 += t3 * w3v[30]; z7 += t3 * w3v[31];

        c0 = n0; c1 = n1; c2 = n2; c3 = n3; c4 = n4;
        c5 = n5; c6 = n6; c7 = n7; c8 = n8;
    }

    // sale contribution (combined index 56)
    {
        float sv = sale[b];
        const f16v* w3s = (const f16v*)(W3 + (size_t)56 * FH);
        z0 += sv * w3s[0]; z1 += sv * w3s[1]; z2 += sv * w3s[2]; z3 += sv * w3s[3];
        z4 += sv * w3s[4]; z5 += sv * w3s[5]; z6 += sv * w3s[6]; z7 += sv * w3s[7];
    }

    // relu z
    z0 = __builtin_elementwise_max(z0, (f16v)0.f);
    z1 = __builtin_elementwise_max(z1, (f16v)0.f);
    z2 = __builtin_elementwise_max(z2, (f16v)0.f);
    z3 = __builtin_elementwise_max(z3, (f16v)0.f);
    z4 = __builtin_elementwise_max(z4, (f16v)0.f);
    z5 = __builtin_elementwise_max(z5, (f16v)0.f);
    z6 = __builtin_elementwise_max(z6, (f16v)0.f);
    z7 = __builtin_elementwise_max(z7, (f16v)0.f);

    // out[k] = z . W4T[k,:] + b4[k]
    size_t ob = (size_t)b * AD;
    #pragma unroll 1
    for (int k = 0; k < 2 * AD; ++k) {
        const f16v* wv = (const f16v*)(W4T + (size_t)k * FH);
        f16v a = z0 * wv[0];
        a += z1 * wv[1];
        a += z2 * wv[2];
        a += z3 * wv[3];
        a += z4 * wv[4];
        a += z5 * wv[5];
        a += z6 * wv[6];
        a += z7 * wv[7];
        float p0 = (a[0] + a[1]) + (a[2] + a[3]);
        float p1 = (a[4] + a[5]) + (a[6] + a[7]);
        float p2 = (a[8] + a[9]) + (a[10] + a[11]);
        float p3 = (a[12] + a[13]) + (a[14] + a[15]);
        float v = ((p0 + p1) + (p2 + p3)) + b4[k];
        if (k < AD) {
            float t = fminf(fmaxf(v, -20.f), 20.f);
            float e = __expf(2.f * t);
            om[ob + k] = (e - 1.f) / (e + 1.f);
        } else {
            os[ob + (k - AD)] = __expf(v);
        }
    }
}

extern "C" void kernel_launch(void* const* d_in, const int* in_sizes, int n_in,
                              void* d_out, int out_size, void* d_ws, size_t ws_size,
                              hipStream_t stream) {
    const float* x    = (const float*)d_in[0];
    const float* sale = (const float*)d_in[1];
    const float* W1   = (const float*)d_in[2];
    const float* b1   = (const float*)d_in[3];
    const float* W2   = (const float*)d_in[4];
    const float* b2   = (const float*)d_in[5];
    const float* W3   = (const float*)d_in[6];
    const float* b3   = (const float*)d_in[7];
    const float* W4   = (const float*)d_in[8];
    const float* b4   = (const float*)d_in[9];

    int B = in_sizes[1];                       // sale_predictions is [B,1]
    float* om = (float*)d_out;                 // action_mean flat [B*15]
    float* os = om + (size_t)B * AD;           // action_std  flat [B*15]
    float* W4T = (float*)d_ws;                 // [30,128]

    w4t_kernel<<<(FH * 2 * AD + 255) / 256, 256, 0, stream>>>(W4, W4T);
    int grid = (B + 255) / 256;
    actor_fused<<<grid, 256, 0, stream>>>(x, sale, W1, b1, W2, b2, W3, b3,
                                          W4T, b4, om, os, B);
}

// Round 3
// 309.141 us; speedup vs baseline: 1.0965x; 1.0192x over previous
//
#include <hip/hip_runtime.h>

// Actor MLP, B=262144 rows, fp32. One thread per row; z[128] as 8 named
// ext_vector(16) SSA values. R2 failure: default VGPR budget (~128, 4 waves/EU
// heuristic) forced z to spill (VGPR_Count=108, VALUBusy 22%, latency-bound).
// Fix: __launch_bounds__(256, 2) -> 256-VGPR cap, z stays resident.
// Input rows loaded as dwordx4 pairs (4B-aligned ok on gfx950).

typedef float f16v __attribute__((ext_vector_type(16)));
typedef float f4v  __attribute__((ext_vector_type(4)));

constexpr int NG = 14, GI = 9, SH = 16, SO = 4, FH = 128, AD = 15;

__device__ __forceinline__ f4v load4u(const float* p) {
    f4v v; __builtin_memcpy(&v, p, 16); return v;   // align-4 dwordx4
}

__global__ void w4t_kernel(const float* __restrict__ W4, float* __restrict__ W4T) {
    int t = blockIdx.x * 256 + threadIdx.x;
    if (t < FH * 2 * AD) {
        int j = t / (2 * AD), k = t % (2 * AD);   // W4[j][k]
        W4T[(size_t)k * FH + j] = W4[t];
    }
}

__global__ __launch_bounds__(256, 2) void actor_fused(
    const float* __restrict__ x,     // [B,126]
    const float* __restrict__ sale,  // [B,1]
    const float* __restrict__ W1,    // [9,16]
    const float* __restrict__ b1,    // [16]
    const float* __restrict__ W2,    // [16,4]
    const float* __restrict__ b2,    // [4]
    const float* __restrict__ W3,    // [57,128]
    const float* __restrict__ b3,    // [128]
    const float* __restrict__ W4T,   // [30,128] (transposed, in ws)
    const float* __restrict__ b4,    // [30]
    float* __restrict__ om, float* __restrict__ os, int B)
{
    int b = blockIdx.x * blockDim.x + threadIdx.x;
    if (b >= B) return;
    const float* xr = x + (size_t)b * (NG * GI);

    const f16v* b3v = (const f16v*)b3;
    f16v z0 = b3v[0], z1 = b3v[1], z2 = b3v[2], z3 = b3v[3],
         z4 = b3v[4], z5 = b3v[5], z6 = b3v[6], z7 = b3v[7];

    const f16v* w1v = (const f16v*)W1;   // row i = 16 floats
    const f4v*  w2v = (const f4v*)W2;    // row i = 4 floats
    const f16v  b1v = *(const f16v*)b1;
    const f4v   b2v = *(const f4v*)b2;

    // software-pipelined input row: 2 x dwordx4 + 1 scalar, one group ahead
    f4v  ca = load4u(xr + 0), cb = load4u(xr + 4);
    float cs = xr[8];

    #pragma unroll 1
    for (int g = 0; g < NG; ++g) {
        f4v na, nb; float ns;
        if (g + 1 < NG) {
            const float* xn = xr + (g + 1) * GI;
            na = load4u(xn); nb = load4u(xn + 4); ns = xn[8];
        } else {
            na = (f4v)0.f; nb = (f4v)0.f; ns = 0.f;
        }

        // h = relu(b1 + x_g @ W1)
        f16v h = b1v;
        h += ca[0] * w1v[0]; h += ca[1] * w1v[1]; h += ca[2] * w1v[2];
        h += ca[3] * w1v[3]; h += cb[0] * w1v[4]; h += cb[1] * w1v[5];
        h += cb[2] * w1v[6]; h += cb[3] * w1v[7]; h += cs    * w1v[8];
        h = __builtin_elementwise_max(h, (f16v)0.f);

        // s = relu(b2 + h @ W2)
        f4v s = b2v;
        s += h[0]  * w2v[0];  s += h[1]  * w2v[1];  s += h[2]  * w2v[2];  s += h[3]  * w2v[3];
        s += h[4]  * w2v[4];  s += h[5]  * w2v[5];  s += h[6]  * w2v[6];  s += h[7]  * w2v[7];
        s += h[8]  * w2v[8];  s += h[9]  * w2v[9];  s += h[10] * w2v[10]; s += h[11] * w2v[11];
        s += h[12] * w2v[12]; s += h[13] * w2v[13]; s += h[14] * w2v[14]; s += h[15] * w2v[15];
        s = __builtin_elementwise_max(s, (f4v)0.f);

        // z += s_o * W3row(g*4+o), o=0..3
        const f16v* w3v = (const f16v*)(W3 + (size_t)(g * SO) * FH);
        float t0 = s[0], t1 = s[1], t2 = s[2], t3 = s[3];
        z0 += t0 * w3v[0];  z1 += t0 * w3v[1];  z2 += t0 * w3v[2];  z3 += t0 * w3v[3];
        z4 += t0 * w3v[4];  z5 += t0 * w3v[5];  z6 += t0 * w3v[6];  z7 += t0 * w3v[7];
        z0 += t1 * w3v[8];  z1 += t1 * w3v[9];  z2 += t1 * w3v[10]; z3 += t1 * w3v[11];
        z4 += t1 * w3v[12]; z5 += t1 * w3v[13]; z6 += t1 * w3v[14]; z7 += t1 * w3v[15];
        z0 += t2 * w3v[16]; z1 += t2 * w3v[17]; z2 += t2 * w3v[18]; z3 += t2 * w3v[19];
        z4 += t2 * w3v[20]; z5 += t2 * w3v[21]; z6 += t2 * w3v[22]; z7 += t2 * w3v[23];
        z0 += t3 * w3v[24]; z1 += t3 * w3v[25]; z2 += t3 * w3v[26]; z3 += t3 * w3v[27];
        z4 += t3 * w3v[28]; z5 += t3 * w3v[29]; z6 += t3 * w3v[30]; z7 += t3 * w3v[31];

        ca = na; cb = nb; cs = ns;
    }

    // sale contribution (combined index 56)
    {
        float sv = sale[b];
        const f16v* w3s = (const f16v*)(W3 + (size_t)56 * FH);
        z0 += sv * w3s[0]; z1 += sv * w3s[1]; z2 += sv * w3s[2]; z3 += sv * w3s[3];
        z4 += sv * w3s[4]; z5 += sv * w3s[5]; z6 += sv * w3s[6]; z7 += sv * w3s[7];
    }

    // relu z
    z0 = __builtin_elementwise_max(z0, (f16v)0.f);
    z1 = __builtin_elementwise_max(z1, (f16v)0.f);
    z2 = __builtin_elementwise_max(z2, (f16v)0.f);
    z3 = __builtin_elementwise_max(z3, (f16v)0.f);
    z4 = __builtin_elementwise_max(z4, (f16v)0.f);
    z5 = __builtin_elementwise_max(z5, (f16v)0.f);
    z6 = __builtin_elementwise_max(z6, (f16v)0.f);
    z7 = __builtin_elementwise_max(z7, (f16v)0.f);

    // out[k] = z . W4T[k,:] + b4[k]
    size_t ob = (size_t)b * AD;
    #pragma unroll 1
    for (int k = 0; k < 2 * AD; ++k) {
        const f16v* wv = (const f16v*)(W4T + (size_t)k * FH);
        f16v a = z0 * wv[0];
        a += z1 * wv[1];
        a += z2 * wv[2];
        a += z3 * wv[3];
        a += z4 * wv[4];
        a += z5 * wv[5];
        a += z6 * wv[6];
        a += z7 * wv[7];
        float p0 = (a[0] + a[1]) + (a[2] + a[3]);
        float p1 = (a[4] + a[5]) + (a[6] + a[7]);
        float p2 = (a[8] + a[9]) + (a[10] + a[11]);
        float p3 = (a[12] + a[13]) + (a[14] + a[15]);
        float v = ((p0 + p1) + (p2 + p3)) + b4[k];
        if (k < AD) {
            float t = fminf(fmaxf(v, -20.f), 20.f);
            float e = __expf(2.f * t);
            om[ob + k] = (e - 1.f) / (e + 1.f);
        } else {
            os[ob + (k - AD)] = __expf(v);
        }
    }
}

extern "C" void kernel_launch(void* const* d_in, const int* in_sizes, int n_in,
                              void* d_out, int out_size, void* d_ws, size_t ws_size,
                              hipStream_t stream) {
    const float* x    = (const float*)d_in[0];
    const float* sale = (const float*)d_in[1];
    const float* W1   = (const float*)d_in[2];
    const float* b1   = (const float*)d_in[3];
    const float* W2   = (const float*)d_in[4];
    const float* b2   = (const float*)d_in[5];
    const float* W3   = (const float*)d_in[6];
    const float* b3   = (const float*)d_in[7];
    const float* W4   = (const float*)d_in[8];
    const float* b4   = (const float*)d_in[9];

    int B = in_sizes[1];                       // sale_predictions is [B,1]
    float* om = (float*)d_out;                 // action_mean flat [B*15]
    float* os = om + (size_t)B * AD;           // action_std  flat [B*15]
    float* W4T = (float*)d_ws;                 // [30,128]

    w4t_kernel<<<(FH * 2 * AD + 255) / 256, 256, 0, stream>>>(W4, W4T);
    int grid = (B + 255) / 256;
    actor_fused<<<grid, 256, 0, stream>>>(x, sale, W1, b1, W2, b2, W3, b3,
                                          W4T, b4, om, os, B);
}